// Round 7
// baseline (304.823 us; speedup 1.0000x reference)
//
#include <hip/hip_runtime.h>
#include <hip/hip_bf16.h>
#include <stdint.h>

#define B_   16
#define CIN  512
#define HW   1600
#define E_   256
#define NTOK 80
#define CG   512
#define COUT 512
#define NHEAD 8
#define HCH  32
#define SP   (42*42)   /* padded spatial 42x42 = 1764 */

typedef __attribute__((ext_vector_type(8))) short bf16x8;
typedef __attribute__((ext_vector_type(4))) float f32x4;

__device__ __forceinline__ unsigned short f2bf(float f) {
  union { float f; unsigned int i; } v; v.f = f;
  unsigned int x = v.i;
  return (unsigned short)((x + 0x7FFFu + ((x >> 16) & 1u)) >> 16);
}

// ---- prep: x [B][CIN][HW] f32 -> xt [B][SP][CIN] bf16 (zero border pad=1) ----
__global__ void k_prep_x(const float* __restrict__ x, unsigned short* __restrict__ xt) {
  __shared__ float tile[32][33];
  int hw0 = blockIdx.x * 32, ci0 = blockIdx.y * 32, b = blockIdx.z;
  int tx = threadIdx.x, ty = threadIdx.y;
  const float* xp = x + ((size_t)b * CIN + ci0) * HW + hw0;
#pragma unroll
  for (int j = 0; j < 4; j++) tile[ty + 8 * j][tx] = xp[(size_t)(ty + 8 * j) * HW + tx];
  __syncthreads();
  int ci = ci0 + tx;
#pragma unroll
  for (int j = 0; j < 4; j++) {
    int hw = hw0 + ty + 8 * j;
    int h = hw / 40, w = hw - h * 40;
    xt[((size_t)b * SP + (size_t)(h + 1) * 42 + (w + 1)) * CIN + ci] = f2bf(tile[tx][ty + 8 * j]);
  }
}

// ---- fused f32 -> bf16 casts: We (32768 x4), Wg (32768 x4), guide (163840 x4) ----
__global__ void k_cast_all(const float* __restrict__ We, unsigned short* __restrict__ web,
                           const float* __restrict__ Wg, unsigned short* __restrict__ wgb,
                           const float* __restrict__ gu, unsigned short* __restrict__ gub) {
  int i = blockIdx.x * 256 + threadIdx.x;
  const float* src; unsigned short* dst; int j;
  if (i < 32768)       { src = We; dst = web; j = i; }
  else if (i < 65536)  { src = Wg; dst = wgb; j = i - 32768; }
  else                 { src = gu; dst = gub; j = i - 65536; }
  float4 v = ((const float4*)src)[j];
  ushort4 o; o.x = f2bf(v.x); o.y = f2bf(v.y); o.z = f2bf(v.z); o.w = f2bf(v.w);
  ((ushort4*)dst)[j] = o;
}

// ==== shared GEMM body: 512 threads, tile 256x256, BK=32, 3-buf dist-2,
//      one counted-vmcnt + one barrier per slab, wave-staggered m-half order ====
// EPI==0: conv1x1 -> et bf16 (BN);  EPI==1: conv3x3 -> out f32 (BN*gate);
// EPI==2: guide GEMM -> gbf bf16 (+bias)
template<int EPI>
__device__ __forceinline__ void gemm_body(
    const unsigned short* __restrict__ Aw, const unsigned short* __restrict__ Bx,
    int m0, int n0,
    const float* __restrict__ g_sc, const float* __restrict__ g_bt,
    const float* __restrict__ attn, float* __restrict__ out,
    unsigned short* __restrict__ ob16, char* LB) {
  constexpr int RS    = (EPI == 1) ? 9 * CIN : CIN;
  constexpr int NSTEP = (EPI == 1) ? 144 : 16;
  int tid = threadIdx.x;
  int lane = tid & 63, wid = tid >> 6;
  int wr = wid >> 2, wc = wid & 3;

  // staging: thread stages 16B granules; A rows rloc,+128; B cols rloc,+128
  int rloc = tid >> 2;
  int kq_g = ((tid & 3) ^ ((tid >> 3) & 3)) * 8;   // source-side involution swizzle
  const unsigned short* pA = Aw + (size_t)(m0 + rloc) * RS + kq_g;
  const unsigned short* pB0;
  const unsigned short* pB1;
  if constexpr (EPI == 2) {
    pB0 = Bx + (size_t)(n0 + rloc) * CIN + kq_g;
    pB1 = pB0 + (size_t)128 * CIN;
  } else {
    int c0 = n0 + rloc, c1 = c0 + 128;
    int b0 = c0 / 1600, hw0 = c0 - b0 * 1600;
    int b1 = c1 / 1600, hw1 = c1 - b1 * 1600;
    int h0 = hw0 / 40, w0 = hw0 - h0 * 40;
    int h1 = hw1 / 40, w1 = hw1 - h1 * 40;
    constexpr int ctr = (EPI == 0) ? 43 : 0;       // 1x1 reads center tap
    pB0 = Bx + ((size_t)b0 * SP + h0 * 42 + w0 + ctr) * CIN + kq_g;
    pB1 = Bx + ((size_t)b1 * SP + h1 * 42 + w1 + ctr) * CIN + kq_g;
  }

  int scnt = 0;
#define GL(src, dst) __builtin_amdgcn_global_load_lds((const __attribute__((address_space(1))) unsigned int*)(src), \
        (__attribute__((address_space(3))) unsigned int*)(dst), 16, 0, 0)
  auto STG = [&](unsigned bo) {
    GL(pA,            LB + bo +     0u + tid * 16u);
    GL(pA + 128 * RS, LB + bo +  8192u + tid * 16u);
    GL(pB0,           LB + bo + 16384u + tid * 16u);
    GL(pB1,           LB + bo + 24576u + tid * 16u);
    pA += 32; pB0 += 32; pB1 += 32;
    if constexpr (EPI == 1) {
      ++scnt;
      if ((scnt % 48) == 0) { pB0 += 19968; pB1 += 19968; }  // tap-row jump
    }
  };

  // fragment offsets (read-side of involution swizzle)
  int frow = lane & 15;
  int sg = ((lane >> 4) ^ ((frow >> 1) & 3)) << 4;
  int aoff[8], boff[4];
#pragma unroll
  for (int i = 0; i < 8; i++) aoff[i] = (wr * 128 + i * 16 + frow) * 64 + sg;
#pragma unroll
  for (int i = 0; i < 4; i++) boff[i] = 16384 + (wc * 64 + i * 16 + frow) * 64 + sg;

  f32x4 acc[8][4] = {};

  STG(0u); STG(32768u);
  unsigned r0 = 0u, r1 = 32768u, r2 = 65536u;
  for (int s = 0; s < NSTEP; ++s) {
    if (s + 1 < NSTEP) { asm volatile("s_waitcnt vmcnt(4)" ::: "memory"); }
    else               { asm volatile("s_waitcnt vmcnt(0)" ::: "memory"); }
    __builtin_amdgcn_s_barrier();            // slab s staged for all waves; r2 free
    __builtin_amdgcn_sched_barrier(0);
    if (s + 2 < NSTEP) STG(r2);              // stage-early: issue before ds_reads
    const char* base = LB + r0;
    bf16x8 bv[4];
#pragma unroll
    for (int i = 0; i < 4; i++) bv[i] = *(const bf16x8*)(base + boff[i]);
    if ((wid & 1) == 0) {                    // even waves: m-half0 then m-half1
      bf16x8 a0[4];
#pragma unroll
      for (int i = 0; i < 4; i++) a0[i] = *(const bf16x8*)(base + aoff[i]);
      __builtin_amdgcn_s_setprio(1);
#pragma unroll
      for (int mi = 0; mi < 4; mi++)
#pragma unroll
        for (int ni = 0; ni < 4; ni++)
          acc[mi][ni] = __builtin_amdgcn_mfma_f32_16x16x32_bf16(a0[mi], bv[ni], acc[mi][ni], 0, 0, 0);
      __builtin_amdgcn_s_setprio(0);
      bf16x8 a1[4];
#pragma unroll
      for (int i = 0; i < 4; i++) a1[i] = *(const bf16x8*)(base + aoff[4 + i]);
      __builtin_amdgcn_s_setprio(1);
#pragma unroll
      for (int mi = 0; mi < 4; mi++)
#pragma unroll
        for (int ni = 0; ni < 4; ni++)
          acc[4 + mi][ni] = __builtin_amdgcn_mfma_f32_16x16x32_bf16(a1[mi], bv[ni], acc[4 + mi][ni], 0, 0, 0);
      __builtin_amdgcn_s_setprio(0);
    } else {                                 // odd waves: m-half1 then m-half0
      bf16x8 a1[4];
#pragma unroll
      for (int i = 0; i < 4; i++) a1[i] = *(const bf16x8*)(base + aoff[4 + i]);
      __builtin_amdgcn_s_setprio(1);
#pragma unroll
      for (int mi = 0; mi < 4; mi++)
#pragma unroll
        for (int ni = 0; ni < 4; ni++)
          acc[4 + mi][ni] = __builtin_amdgcn_mfma_f32_16x16x32_bf16(a1[mi], bv[ni], acc[4 + mi][ni], 0, 0, 0);
      __builtin_amdgcn_s_setprio(0);
      bf16x8 a0[4];
#pragma unroll
      for (int i = 0; i < 4; i++) a0[i] = *(const bf16x8*)(base + aoff[i]);
      __builtin_amdgcn_s_setprio(1);
#pragma unroll
      for (int mi = 0; mi < 4; mi++)
#pragma unroll
        for (int ni = 0; ni < 4; ni++)
          acc[mi][ni] = __builtin_amdgcn_mfma_f32_16x16x32_bf16(a0[mi], bv[ni], acc[mi][ni], 0, 0, 0);
      __builtin_amdgcn_s_setprio(0);
    }
    unsigned t = r0; r0 = r1; r1 = r2; r2 = t;
  }
#undef GL

  const float BN_RSQ = 0.9995003746877732f;  // 1/sqrt(1+1e-3)
  int colb = n0 + wc * 64 + frow;
  int rowb = m0 + wr * 128 + (lane >> 4) * 4;
  if constexpr (EPI == 1) {                  // conv3x3: f32 gated out[b][co][hw]
#pragma unroll
    for (int mi = 0; mi < 8; mi++) {
      int head = (m0 + wr * 128 + mi * 16) >> 6;
      float sc[4], bt[4];
#pragma unroll
      for (int j = 0; j < 4; j++) {
        int co = rowb + mi * 16 + j;
        sc[j] = g_sc[co] * BN_RSQ; bt[j] = g_bt[co];
      }
#pragma unroll
      for (int ni = 0; ni < 4; ni++) {
        int col = colb + ni * 16;
        int b = col / 1600, hw = col - b * 1600;
        float gate = attn[((size_t)b * NHEAD + head) * HW + hw];
#pragma unroll
        for (int j = 0; j < 4; j++) {
          int co = rowb + mi * 16 + j;
          out[((size_t)b * COUT + co) * HW + hw] = (acc[mi][ni][j] * sc[j] + bt[j]) * gate;
        }
      }
    }
  } else if constexpr (EPI == 0) {           // conv1x1: et[b][hw][E] bf16
#pragma unroll
    for (int mi = 0; mi < 8; mi++) {
      float sc[4], bt[4];
#pragma unroll
      for (int j = 0; j < 4; j++) {
        int ech = rowb + mi * 16 + j;
        sc[j] = g_sc[ech] * BN_RSQ; bt[j] = g_bt[ech];
      }
#pragma unroll
      for (int ni = 0; ni < 4; ni++) {
        int col = colb + ni * 16;
        int b = col / 1600, hw = col - b * 1600;
        ushort4 pk;
        pk.x = f2bf(acc[mi][ni][0] * sc[0] + bt[0]);
        pk.y = f2bf(acc[mi][ni][1] * sc[1] + bt[1]);
        pk.z = f2bf(acc[mi][ni][2] * sc[2] + bt[2]);
        pk.w = f2bf(acc[mi][ni][3] * sc[3] + bt[3]);
        *(ushort4*)(ob16 + ((size_t)b * HW + hw) * E_ + (rowb + mi * 16)) = pk;
      }
    }
  } else {                                   // guide fc: gbf[token][e] bf16 (+bg)
#pragma unroll
    for (int mi = 0; mi < 8; mi++) {
      float bt[4];
#pragma unroll
      for (int j = 0; j < 4; j++) bt[j] = g_bt[rowb + mi * 16 + j];
#pragma unroll
      for (int ni = 0; ni < 4; ni++) {
        int col = colb + ni * 16;
        ushort4 pk;
        pk.x = f2bf(acc[mi][ni][0] + bt[0]);
        pk.y = f2bf(acc[mi][ni][1] + bt[1]);
        pk.z = f2bf(acc[mi][ni][2] + bt[2]);
        pk.w = f2bf(acc[mi][ni][3] + bt[3]);
        *(ushort4*)(ob16 + (size_t)col * E_ + (rowb + mi * 16)) = pk;
      }
    }
  }
}

// ---- stage1: wg 0..99 conv1x1; wg 100..104 guide GEMM; wg 105..254 prep_wp ----
__global__ __launch_bounds__(512, 1)
void k_stage1(const unsigned short* __restrict__ web, const unsigned short* __restrict__ wgb,
              const unsigned short* __restrict__ xt,  const unsigned short* __restrict__ gub,
              const float* __restrict__ gamma_e, const float* __restrict__ beta_e,
              const float* __restrict__ bg,
              unsigned short* __restrict__ et, unsigned short* __restrict__ gbf,
              const float* __restrict__ Wp, unsigned short* __restrict__ wpb2) {
  __shared__ unsigned short L[3 * 16384];
  int wg = blockIdx.x;
  if (wg < 100) {
    gemm_body<0>(web, xt, 0, wg * 256, gamma_e, beta_e, nullptr, nullptr, et, (char*)L);
  } else if (wg < 105) {
    gemm_body<2>(wgb, gub, 0, (wg - 100) * 256, nullptr, bg, nullptr, nullptr, gbf, (char*)L);
  } else {
    // prep Wp [COUT][CIN][3][3] f32 -> wpb2 [COUT][9*CIN] bf16, grid-stride
    int g = (wg - 105) * 512 + threadIdx.x;
    for (int idx = g; idx < COUT * CIN; idx += 150 * 512) {
      int co = idx >> 9, ci = idx & 511;
      const float* s = Wp + (size_t)idx * 9;
#pragma unroll
      for (int t = 0; t < 9; t++) wpb2[(size_t)co * (9 * CIN) + t * CIN + ci] = f2bf(s[t]);
    }
  }
}

// ---- conv3x3 gated: 200 wgs, XCD-swizzled ----
__global__ __launch_bounds__(512, 1)
void k_conv3(const unsigned short* __restrict__ wpb2, const unsigned short* __restrict__ xt,
             const float* __restrict__ gamma_p, const float* __restrict__ beta_p,
             const float* __restrict__ attn, float* __restrict__ out) {
  __shared__ unsigned short L[3 * 16384];
  int wg = blockIdx.x;
  int w = (wg & 7) * 25 + (wg >> 3);         // bijective XCD swizzle (200%8==0)
  int m0 = (w / 100) * 256, n0 = (w % 100) * 256;
  gemm_body<1>(wpb2, xt, m0, n0, gamma_p, beta_p, attn, out, nullptr, (char*)L);
}

// ---- attn via MFMA: per (b,head): [HW x 32] . [32 x 80] -> max over 80, sigmoid ----
__global__ void k_attn_mfma(const unsigned short* __restrict__ et, const unsigned short* __restrict__ gbf,
                            const float* __restrict__ head_bias, float* __restrict__ attn) {
  __shared__ unsigned short gs[NTOK * HCH];   // [token][c] bf16, 5 KB
  int b = blockIdx.z, m = blockIdx.y;
  int tid = threadIdx.x, lane = tid & 63, wid = tid >> 6;
  for (int i = tid; i < NTOK * HCH / 8; i += 256) {
    int n = i >> 2, c = (i & 3) * 8;
    *(bf16x8*)&gs[n * HCH + c] = *(const bf16x8*)&gbf[((size_t)b * NTOK + n) * E_ + m * HCH + c];
  }
  __syncthreads();
  int col = lane & 15, kq = (lane >> 4) * 8;
  bf16x8 bfr[5];
#pragma unroll
  for (int ni = 0; ni < 5; ni++)
    bfr[ni] = *(const bf16x8*)&gs[(ni * 16 + col) * HCH + kq];

  int hw0 = blockIdx.x * 256 + wid * 64;
  bf16x8 afr[4];
#pragma unroll
  for (int mi = 0; mi < 4; mi++) {
    int hw = hw0 + mi * 16 + col; if (hw > HW - 1) hw = HW - 1;
    afr[mi] = *(const bf16x8*)&et[((size_t)b * HW + hw) * E_ + m * HCH + kq];
  }
  float hb = head_bias[m];
  float* attnp = attn + ((size_t)b * NHEAD + m) * HW;
#pragma unroll
  for (int mi = 0; mi < 4; mi++) {
    f32x4 d[5];
#pragma unroll
    for (int ni = 0; ni < 5; ni++) {
      f32x4 z = {0.f, 0.f, 0.f, 0.f};
      d[ni] = __builtin_amdgcn_mfma_f32_16x16x32_bf16(afr[mi], bfr[ni], z, 0, 0, 0);
    }
#pragma unroll
    for (int j = 0; j < 4; j++) {
      float v = fmaxf(fmaxf(fmaxf(d[0][j], d[1][j]), fmaxf(d[2][j], d[3][j])), d[4][j]);
      v = fmaxf(v, __shfl_xor(v, 1, 16));
      v = fmaxf(v, __shfl_xor(v, 2, 16));
      v = fmaxf(v, __shfl_xor(v, 4, 16));
      v = fmaxf(v, __shfl_xor(v, 8, 16));
      if (col == j) {
        int hwout = hw0 + mi * 16 + (lane >> 4) * 4 + j;
        if (hwout < HW)
          attnp[hwout] = 1.0f / (1.0f + __expf(-(v * 0.17677669529663687f + hb)));
      }
    }
  }
}

extern "C" void kernel_launch(void* const* d_in, const int* in_sizes, int n_in,
                              void* d_out, int out_size, void* d_ws, size_t ws_size,
                              hipStream_t stream) {
  const float* x         = (const float*)d_in[0];
  const float* guide     = (const float*)d_in[1];
  const float* We        = (const float*)d_in[2];
  const float* gamma_e   = (const float*)d_in[3];
  const float* beta_e    = (const float*)d_in[4];
  const float* Wg        = (const float*)d_in[5];
  const float* bg        = (const float*)d_in[6];
  const float* head_bias = (const float*)d_in[7];
  const float* Wp        = (const float*)d_in[8];
  const float* gamma_p   = (const float*)d_in[9];
  const float* beta_p    = (const float*)d_in[10];
  float* out = (float*)d_out;

  char* ws = (char*)d_ws;
  size_t off = 0;
  auto alloc = [&](size_t bytes) { char* p = ws + off; off += (bytes + 255) & ~(size_t)255; return p; };
  unsigned short* xt   = (unsigned short*)alloc((size_t)B_ * SP * CIN * 2);
  unsigned short* wpb2 = (unsigned short*)alloc((size_t)COUT * 9 * CIN * 2);
  unsigned short* web  = (unsigned short*)alloc((size_t)E_ * CIN * 2);
  unsigned short* wgb  = (unsigned short*)alloc((size_t)E_ * CG * 2);
  unsigned short* gub  = (unsigned short*)alloc((size_t)B_ * NTOK * CG * 2);
  unsigned short* gbf  = (unsigned short*)alloc((size_t)B_ * NTOK * E_ * 2);
  unsigned short* et   = (unsigned short*)alloc((size_t)B_ * HW * E_ * 2);
  float* attn          = (float*)alloc((size_t)B_ * NHEAD * HW * 4);

  hipMemsetAsync(xt, 0, (size_t)B_ * SP * CIN * 2, stream);
  k_prep_x<<<dim3(50, 16, B_), dim3(32, 8), 0, stream>>>(x, xt);
  k_cast_all<<<dim3(896), dim3(256), 0, stream>>>(We, web, Wg, wgb, guide, gub);
  k_stage1<<<dim3(255), dim3(512), 0, stream>>>(web, wgb, xt, gub, gamma_e, beta_e, bg, et, gbf, Wp, wpb2);
  k_attn_mfma<<<dim3(7, NHEAD, B_), dim3(256), 0, stream>>>(et, gbf, head_bias, attn);
  k_conv3<<<dim3(200), dim3(512), 0, stream>>>(wpb2, xt, gamma_p, beta_p, attn, out);
}